// Round 1
// baseline (234.396 us; speedup 1.0000x reference)
//
#include <hip/hip_runtime.h>

// NarrativeClassificationLoss — v5: column-slice decomposition.
// R4 post-mortem of v4: ncl_main 62us (latency-bound: occ 37%, VALU 28%,
// HBM 19%) but total 191us -> ~130us lost in reduce1/reduce2/finalize +
// 14MB partial-table round trip (WRITE_SIZE 13.9MB).
// v5: each block owns a 32-subcol+4-narrcol stripe x 256 rows. pos_weight
// is per-column, so weighted BCE = pw_c*A_c + C_c with A/C/ssum held in
// registers, wave-butterfly + LDS fold, ~111 atomicAdds/block into ONE
// 13.9KB table. No reduce kernels. Grid 2048 (8 blocks/CU potential).
//
// B=16384, N_NARR=128, N_SUB=1024, K=8, GAMMA=2, weights (1,1,0.5).

#define BDIM 256
#define NROWS 16384
#define NNARR 128
#define NSUB 1024

#define NSLICES 32                        // 1024/32 sub cols per slice
#define SUBC 32
#define NARRC 4
#define ROWS_PER_CHUNK 256
#define NCHUNKS (NROWS / ROWS_PER_CHUNK)  // 64
#define NBLOCKS (NCHUNKS * NSLICES)       // 2048
#define ITERS (ROWS_PER_CHUNK / 32)       // 8 (32 rows per pass of 256 thr)

// single global table layout (floats)
#define WS_AN    0      // [128]  sum_b y*sp(-x)          (narrative)
#define WS_CN    128    // [128]  sum_b (1-y)*sp(x)
#define WS_NSUM  256    // [128]  col sums of narrative labels
#define WS_AS    384    // [1024] sum_b pos*y*sp(-x)      (subnarrative)
#define WS_CS    1408   // [1024] sum_b pos*(1-y)*sp(x)
#define WS_SSUM  2432   // [1024] col sums of sub labels
#define WS_FN    3456   // focal narrative sum
#define WS_FS    3457   // focal subnarrative sum
#define WS_HIER  3458   // hierarchy sum
#define WS_FLOATS 3459

__device__ __forceinline__ void bce_pieces(float x, float& sp_p, float& sp_m, float& sig) {
    float a = fabsf(x);
    float e = __expf(-a);              // exp(-|x|) in (0,1]
    float l = __logf(1.0f + e);        // ~log1p(e); err ~1e-7, fine after /2M
    sp_p = fmaxf(x, 0.0f) + l;
    sp_m = sp_p - x;
    float inv = __builtin_amdgcn_rcpf(1.0f + e);
    sig = (x >= 0.0f) ? inv : e * inv;
}

__global__ __launch_bounds__(BDIM, 6) void ncl_main(
    const float* __restrict__ nlog, const float* __restrict__ slog,
    const int*   __restrict__ nlab, const int*   __restrict__ slab,
    float* __restrict__ ws)
{
    __shared__ float lsub[4][8][12];   // per-wave per-quad {As,Cs,ss}
    __shared__ float lnar[4][4][3];    // per-wave per-narrcol {An,Cn,ns}
    __shared__ float lsc[4][3];        // per-wave {fn,fs,hier}

    const int t     = threadIdx.x;
    const int j     = blockIdx.x & (NSLICES - 1);   // col slice
    const int chunk = blockIdx.x >> 5;              // row chunk
    const int q  = t & 7;        // sub col-quad within slice (4 cols)
    const int ro = t >> 3;       // row offset 0..31 within a pass
    const int cl = q >> 1;       // local narr col 0..3 (pair of quads = 1 group)
    const bool evenq = (q & 1) == 0;

    const int r0 = chunk * ROWS_PER_CHUNK + ro;
    const float* sp = slog + (size_t)r0 * NSUB  + j * SUBC  + 4 * q;
    const int*   yp = slab + (size_t)r0 * NSUB  + j * SUBC  + 4 * q;
    const float* np = nlog + (size_t)r0 * NNARR + j * NARRC + cl;
    const int*   mp = nlab + (size_t)r0 * NNARR + j * NARRC + cl;

    float As[4] = {0,0,0,0}, Cs[4] = {0,0,0,0}, ssum[4] = {0,0,0,0};
    float An = 0.f, Cn = 0.f, ns = 0.f, fn = 0.f, fs = 0.f, hier = 0.f;

    #pragma unroll 2
    for (int it = 0; it < ITERS; ++it) {
        const size_t so = (size_t)it * 32 * NSUB;
        const size_t no = (size_t)it * 32 * NNARR;
        const float4 xs = *(const float4*)(sp + so);
        const int4   ys = *(const int4*)  (yp + so);
        const float  nx   = np[no];
        const float  posv = (float)mp[no];   // narr label == pos mask

        float nsp_p, nsp_m, nsig;
        bce_pieces(nx, nsp_p, nsp_m, nsig);

        const float xv[4] = {xs.x, xs.y, xs.z, xs.w};
        const float yv[4] = {(float)ys.x, (float)ys.y, (float)ys.z, (float)ys.w};
        float mymax = 0.0f;
        #pragma unroll
        for (int k = 0; k < 4; ++k) {
            float sp_p, sp_m, sig;
            bce_pieces(xv[k], sp_p, sp_m, sig);
            float y = yv[k];
            As[k]   += posv * y * sp_m;
            Cs[k]   += posv * (1.0f - y) * sp_p;
            ssum[k] += y;
            float om = 1.0f - sig;
            fs += om * om * y * (-sp_m);     // log_sigmoid(x) = -softplus(-x)
            mymax = fmaxf(mymax, sig);
        }
        // group of 8 sub cols = adjacent quad pair (t, t^1): same row, same cl
        float gmax = fmaxf(mymax, __shfl_xor(mymax, 1, 64));
        if (evenq) {
            hier += fmaxf(gmax - nsig, 0.0f) * posv;
            An += posv * nsp_m;
            Cn += (1.0f - posv) * nsp_p;
            ns += posv;
            float om = 1.0f - nsig;
            fn += om * om * posv * (-nsp_m);
        }
    }

    // butterfly over the 8 same-quad lanes of each wave (strides 8,16,32).
    // Narr values live only on even-q lanes; odd-q lanes carry zeros.
    #pragma unroll
    for (int m = 8; m <= 32; m <<= 1) {
        #pragma unroll
        for (int k = 0; k < 4; ++k) {
            As[k]   += __shfl_xor(As[k],   m, 64);
            Cs[k]   += __shfl_xor(Cs[k],   m, 64);
            ssum[k] += __shfl_xor(ssum[k], m, 64);
        }
        An += __shfl_xor(An, m, 64);
        Cn += __shfl_xor(Cn, m, 64);
        ns += __shfl_xor(ns, m, 64);
    }
    // full-wave butterfly for the scalar partials
    #pragma unroll
    for (int m = 1; m <= 32; m <<= 1) {
        fn   += __shfl_xor(fn,   m, 64);
        fs   += __shfl_xor(fs,   m, 64);
        hier += __shfl_xor(hier, m, 64);
    }

    const int w = t >> 6, lane = t & 63;
    if (lane < 8) {
        #pragma unroll
        for (int k = 0; k < 4; ++k) {
            lsub[w][lane][k]     = As[k];
            lsub[w][lane][4 + k] = Cs[k];
            lsub[w][lane][8 + k] = ssum[k];
        }
        if ((lane & 1) == 0) {
            lnar[w][lane >> 1][0] = An;
            lnar[w][lane >> 1][1] = Cn;
            lnar[w][lane >> 1][2] = ns;
        }
    }
    if (lane == 0) { lsc[w][0] = fn; lsc[w][1] = fs; lsc[w][2] = hier; }
    __syncthreads();

    if (t < 8) {
        float a[12];
        #pragma unroll
        for (int k = 0; k < 12; ++k)
            a[k] = lsub[0][t][k] + lsub[1][t][k] + lsub[2][t][k] + lsub[3][t][k];
        const int col = j * SUBC + 4 * t;
        #pragma unroll
        for (int k = 0; k < 4; ++k) {
            atomicAdd(ws + WS_AS   + col + k, a[k]);
            atomicAdd(ws + WS_CS   + col + k, a[4 + k]);
            atomicAdd(ws + WS_SSUM + col + k, a[8 + k]);
        }
    } else if (t < 12) {
        const int c = t - 8;
        float a0 = lnar[0][c][0] + lnar[1][c][0] + lnar[2][c][0] + lnar[3][c][0];
        float a1 = lnar[0][c][1] + lnar[1][c][1] + lnar[2][c][1] + lnar[3][c][1];
        float a2 = lnar[0][c][2] + lnar[1][c][2] + lnar[2][c][2] + lnar[3][c][2];
        atomicAdd(ws + WS_AN   + j * NARRC + c, a0);
        atomicAdd(ws + WS_CN   + j * NARRC + c, a1);
        atomicAdd(ws + WS_NSUM + j * NARRC + c, a2);
    } else if (t == 12) {
        float a = lsc[0][0] + lsc[1][0] + lsc[2][0] + lsc[3][0];
        float b = lsc[0][1] + lsc[1][1] + lsc[2][1] + lsc[3][1];
        float c = lsc[0][2] + lsc[1][2] + lsc[2][2] + lsc[3][2];
        atomicAdd(ws + WS_FN,   a);
        atomicAdd(ws + WS_FS,   b);
        atomicAdd(ws + WS_HIER, c);
    }
}

__global__ __launch_bounds__(1024) void ncl_finalize(const float* __restrict__ ws,
                                                     float* __restrict__ out)
{
    __shared__ float sr[3][16];
    const int t = threadIdx.x;
    const float Bf = (float)NROWS;

    float s_sub = ws[WS_SSUM + t];
    float spw   = fminf(fmaxf((Bf - s_sub) / (s_sub + 1e-6f), 1.0f), 50.0f);
    float sub_part = spw * ws[WS_AS + t] + ws[WS_CS + t];

    float narr_part = 0.f, valid_part = 0.f;
    if (t < NNARR) {
        float s = ws[WS_NSUM + t];
        float npw = fminf(fmaxf((Bf - s) / (s + 1e-6f), 1.0f), 50.0f);
        narr_part  = npw * ws[WS_AN + t] + ws[WS_CN + t];
        valid_part = s;
    }

    #pragma unroll
    for (int off = 32; off; off >>= 1) {
        sub_part   += __shfl_down(sub_part,   off, 64);
        narr_part  += __shfl_down(narr_part,  off, 64);
        valid_part += __shfl_down(valid_part, off, 64);
    }
    if ((t & 63) == 0) {
        int w = t >> 6;
        sr[0][w] = sub_part; sr[1][w] = narr_part; sr[2][w] = valid_part;
    }
    __syncthreads();
    if (t == 0) {
        float sub_tot = 0.f, narr_tot = 0.f, valid = 0.f;
        #pragma unroll
        for (int i = 0; i < 16; ++i) { sub_tot += sr[0][i]; narr_tot += sr[1][i]; valid += sr[2][i]; }

        float narrative_loss = narr_tot / (Bf * (float)NNARR);
        float sub_loss = (valid > 0.0f) ? (sub_tot * (1.0f / 8.0f)) / fmaxf(valid, 1.0f) : 0.0f;
        float nf = ws[WS_FN] / (Bf * (float)NNARR);
        float sf = ws[WS_FS] / (Bf * (float)NSUB);
        float hier_loss = ws[WS_HIER] / Bf;

        out[0] = (narrative_loss - 0.1f * nf)
               + (sub_loss       - 0.1f * sf)
               + 0.5f * hier_loss;
    }
}

extern "C" void kernel_launch(void* const* d_in, const int* in_sizes, int n_in,
                              void* d_out, int out_size, void* d_ws, size_t ws_size,
                              hipStream_t stream) {
    const float* nlog = (const float*)d_in[0];
    const float* slog = (const float*)d_in[1];
    const int*   nlab = (const int*)d_in[2];
    const int*   slab = (const int*)d_in[3];
    float* ws  = (float*)d_ws;
    float* out = (float*)d_out;

    hipMemsetAsync(ws, 0, WS_FLOATS * sizeof(float), stream);
    ncl_main<<<NBLOCKS, BDIM, 0, stream>>>(nlog, slog, nlab, slab, ws);
    ncl_finalize<<<1, 1024, 0, stream>>>(ws, out);
}